// Round 3
// baseline (878.791 us; speedup 1.0000x reference)
//
#include <hip/hip_runtime.h>

#define NN 40000
#define EE 640000

typedef unsigned short u16;
typedef unsigned int u32;
typedef __attribute__((ext_vector_type(8))) short short8;
typedef __attribute__((ext_vector_type(4))) float f32x4;

__device__ __forceinline__ float bf2f(u16 b){ u32 u=((u32)b)<<16; float f; __builtin_memcpy(&f,&u,4); return f; }
__device__ __forceinline__ u16 f2bf(float f){ u32 u; __builtin_memcpy(&u,&f,4); u = (u + 0x7fffu + ((u>>16)&1u))>>16; return (u16)u; }

#define MFMA __builtin_amdgcn_mfma_f32_16x16x32_bf16

// ---- LDS layout (bytes) ----
// w1 frags [4kt][16ct][64lane][8] bf16 : 65536 @ 0   (mode2: [16ct][64][8] = 16KB)
// w2 frags [8kt2][8oc][64lane][8] bf16 : 65536 @ 65536
// b1s f32[256]                         : 1024  @ 131072
// b2s f32[128]                         : 512   @ 132096
// stg 8 waves * 32 rows * 40 u16       : 20480 @ 132608
#define SMEM_BYTES 153088

// MODE 0: node msg : A = hbf(bf16), out16 = bf16(MLP(h)+b2), 32 rows/tile
// MODE 1: node upd : A0 = hbf, A1 = bf16(aggr_f32/deg), 16 rows/tile
//                    v = c0+c1+2*b2; hmaxf = max(hmaxf,v); out16 = bf16(v)
// MODE 2: edge     : A = edge_attr(f32->bf16, K=8 zero-padded), w1g=W1'=edge_w@msg_w1
//                    v = c + b2 + mhb[src]; atomicAdd(aggr[dst], v)
template<int MODE>
__global__ __launch_bounds__(512, 1)
void mlp_kernel(const u16* __restrict__ xa, const float* __restrict__ xaf,
                const float* __restrict__ eattr, const int* __restrict__ deg,
                const float* __restrict__ w1g, const float* __restrict__ b1g,
                const float* __restrict__ w2g, const float* __restrict__ b2g,
                const int* __restrict__ eidx, const u16* __restrict__ mhb,
                float* __restrict__ aggr, u16* __restrict__ out16,
                float* __restrict__ hmaxf, int ntiles)
{
    extern __shared__ char smem[];
    short8* w1f = (short8*)smem;
    short8* w2f = (short8*)(smem + 65536);
    u16*    w1u = (u16*)smem;
    u16*    w2u = (u16*)(smem + 65536);
    float*  b1s = (float*)(smem + 131072);
    float*  b2s = (float*)(smem + 132096);

    const int tid = threadIdx.x;

    // ---- fill weights (f32 global -> bf16 fragments) ----
    if (MODE == 2){
        // W1' is [8][256] f32; B-frag elem j of lane l = W1'[(l>>4)*8+j][ct*16+(l&15)]
        // only g==0 rows (k<8) are real; rest zero (A is zero there too).
        for (int idx = tid; idx < 16*64; idx += 512){
            int ct = idx >> 6, lane = idx & 63, g = (lane >> 4), c = lane & 15;
            short8 v = (short8){0,0,0,0,0,0,0,0};
            if (g == 0){
                #pragma unroll
                for (int j = 0; j < 8; ++j) v[j] = (short)f2bf(w1g[j*256 + ct*16 + c]);
            }
            w1f[idx] = v;
        }
    } else {
        for (int idx = tid; idx < 128*256; idx += 512){
            int k = idx >> 8, n = idx & 255;
            w1u[(((k>>5)*16 + (n>>4))*64 + ((k>>3)&3)*16 + (n&15))*8 + (k&7)] = f2bf(w1g[idx]);
        }
    }
    for (int idx = tid; idx < 256*128; idx += 512){
        int k = idx >> 7, n = idx & 127;
        w2u[(((k>>5)*8 + (n>>4))*64 + ((k>>3)&3)*16 + (n&15))*8 + (k&7)] = f2bf(w2g[idx]);
    }
    for (int idx = tid; idx < 256; idx += 512) b1s[idx] = b1g[idx];
    for (int idx = tid; idx < 128; idx += 512) b2s[idx] = b2g[idx];
    __syncthreads();

    const int wave = tid >> 6, lane = tid & 63;
    const int g = lane >> 4, c16 = lane & 15;
    u16* stg = (u16*)(smem + 132608) + wave*1280;   // 32 rows * 40 u16 (80B stride)

    const int wid0 = blockIdx.x*8 + wave;
    const int nwaves = gridDim.x*8;

    for (int t = wid0; t < ntiles; t += nwaves) {
        short8 a[2][4];

        if (MODE == 2) {
            // A-frag from edge_attr f32 (K=8, zero-padded to 32)
            #pragma unroll
            for (int sub = 0; sub < 2; ++sub){
                int e = t*32 + sub*16 + c16;
                f32x4 e0 = *(const f32x4*)(eattr + e*8);
                f32x4 e1 = *(const f32x4*)(eattr + e*8 + 4);
                short8 v;
                #pragma unroll
                for (int j = 0; j < 4; ++j){
                    v[j]   = (short)f2bf(e0[j]);
                    v[4+j] = (short)f2bf(e1[j]);
                }
                if (g != 0) v = (short8){0,0,0,0,0,0,0,0};
                a[sub][0] = v;
            }
        } else if (MODE == 0) {
            #pragma unroll
            for (int sub = 0; sub < 2; ++sub){
                int r = t*32 + sub*16 + c16;
                #pragma unroll
                for (int kt = 0; kt < 4; ++kt)
                    a[sub][kt] = *(const short8*)(xa + r*128 + kt*32 + g*8);
            }
        } else {
            int r = t*16 + c16;
            int d = deg[r]; if (d < 1) d = 1;
            float dinv = 1.f / (float)d;
            #pragma unroll
            for (int kt = 0; kt < 4; ++kt){
                a[0][kt] = *(const short8*)(xa + r*128 + kt*32 + g*8);
                f32x4 v0 = *(const f32x4*)(xaf + r*128 + kt*32 + g*8);
                f32x4 v1 = *(const f32x4*)(xaf + r*128 + kt*32 + g*8 + 4);
                short8 xb;
                #pragma unroll
                for (int j = 0; j < 4; ++j){
                    xb[j]   = (short)f2bf(v0[j]*dinv);
                    xb[4+j] = (short)f2bf(v1[j]*dinv);
                }
                a[1][kt] = xb;
            }
        }

        f32x4 oacc[2][8];
        #pragma unroll
        for (int s = 0; s < 2; ++s)
            #pragma unroll
            for (int o = 0; o < 8; ++o) oacc[s][o] = (f32x4){0.f,0.f,0.f,0.f};

        // stage1 (X@W1+b1, ReLU) interleaved with stage2 (H@W2) per 32-col window
        #pragma unroll
        for (int ct = 0; ct < 16; ++ct){
            float bv = b1s[ct*16 + c16];
            f32x4 acc0 = {bv,bv,bv,bv}, acc1 = acc0;
            if (MODE == 2){
                short8 b = w1f[ct*64 + lane];
                acc0 = MFMA(a[0][0], b, acc0, 0, 0, 0);
                acc1 = MFMA(a[1][0], b, acc1, 0, 0, 0);
            } else {
                #pragma unroll
                for (int kt = 0; kt < 4; ++kt){
                    short8 b = w1f[(kt*16 + ct)*64 + lane];
                    acc0 = MFMA(a[0][kt], b, acc0, 0, 0, 0);
                    acc1 = MFMA(a[1][kt], b, acc1, 0, 0, 0);
                }
            }
            int colw = (ct & 1)*16 + c16;
            #pragma unroll
            for (int i = 0; i < 4; ++i){
                int row = g*4 + i;
                stg[row*40 + colw]      = f2bf(fmaxf(acc0[i], 0.f));
                stg[(16+row)*40 + colw] = f2bf(fmaxf(acc1[i], 0.f));
            }
            if (ct & 1){
                int kt2 = ct >> 1;
                short8 a20 = *(const short8*)(stg + c16*40 + g*8);
                short8 a21 = *(const short8*)(stg + (16 + c16)*40 + g*8);
                #pragma unroll
                for (int oc = 0; oc < 8; ++oc){
                    short8 b = w2f[(kt2*8 + oc)*64 + lane];
                    oacc[0][oc] = MFMA(a20, b, oacc[0][oc], 0, 0, 0);
                    oacc[1][oc] = MFMA(a21, b, oacc[1][oc], 0, 0, 0);
                }
            }
        }

        // ---- epilogue ----
        if (MODE == 0) {
            #pragma unroll
            for (int s = 0; s < 2; ++s){
                int rbase = t*32 + s*16 + g*4;
                #pragma unroll
                for (int oc = 0; oc < 8; ++oc){
                    int col = oc*16 + c16; float bb = b2s[col];
                    #pragma unroll
                    for (int i = 0; i < 4; ++i)
                        out16[(rbase + i)*128 + col] = f2bf(oacc[s][oc][i] + bb);
                }
            }
        } else if (MODE == 1) {
            int rbase = t*16 + g*4;
            #pragma unroll
            for (int oc = 0; oc < 8; ++oc){
                int col = oc*16 + c16; float bb2 = 2.f*b2s[col];
                #pragma unroll
                for (int i = 0; i < 4; ++i){
                    float v = oacc[0][oc][i] + oacc[1][oc][i] + bb2;
                    int idx = (rbase + i)*128 + col;
                    float hm = hmaxf[idx];
                    hmaxf[idx] = fmaxf(hm, v);
                    out16[idx] = f2bf(v);
                }
            }
        } else {
            #pragma unroll
            for (int s = 0; s < 2; ++s){
                int ebase = t*32 + s*16 + g*4;
                int srcs[4], dsts[4];
                #pragma unroll
                for (int i = 0; i < 4; ++i){
                    srcs[i] = eidx[ebase + i];
                    dsts[i] = eidx[EE + ebase + i];
                }
                #pragma unroll
                for (int oc = 0; oc < 8; ++oc){
                    int col = oc*16 + c16; float bb = b2s[col];
                    #pragma unroll
                    for (int i = 0; i < 4; ++i){
                        float v = oacc[s][oc][i] + bb + bf2f(mhb[srcs[i]*128 + col]);
                        unsafeAtomicAdd(&aggr[dsts[i]*128 + col], v);
                    }
                }
            }
        }
    }
}

// W1p[l][8][256] = edge_w @ msg_w1[l];  b1p[l][256] = edge_b @ msg_w1[l] + msg_b1[l]
__global__ void prep_kernel(const float* __restrict__ edge_w, const float* __restrict__ edge_b,
                            const float* __restrict__ msg_w1, const float* __restrict__ msg_b1,
                            float* __restrict__ W1p, float* __restrict__ b1p){
    int l = blockIdx.x, n = threadIdx.x;          // 2 blocks x 256 threads
    const float* w1 = msg_w1 + l*128*256;
    float acc = msg_b1[l*256 + n];
    for (int c = 0; c < 128; ++c) acc += edge_b[c] * w1[c*256 + n];
    b1p[l*256 + n] = acc;
    #pragma unroll
    for (int k = 0; k < 8; ++k){
        float a = 0.f;
        for (int c = 0; c < 128; ++c) a += edge_w[k*128 + c] * w1[c*256 + n];
        W1p[(l*8 + k)*256 + n] = a;
    }
}

__global__ void lift_kernel(const float* __restrict__ x, const float* __restrict__ nw,
                            const float* __restrict__ nb, u16* __restrict__ hbf,
                            float* __restrict__ hmaxf){
    int idx = blockIdx.x*blockDim.x + threadIdx.x;
    const int total = NN*128;
    for (; idx < total; idx += gridDim.x*blockDim.x){
        int n = idx >> 7, c = idx & 127;
        const float* xr = x + n*16;
        float acc = nb[c];
        #pragma unroll
        for (int k = 0; k < 16; ++k) acc += xr[k] * nw[k*128 + c];
        hbf[idx] = f2bf(acc);
        hmaxf[idx] = acc;
    }
}

__global__ void deg_kernel(const int* __restrict__ eidx, int* __restrict__ deg){
    int i = blockIdx.x*blockDim.x + threadIdx.x;
    for (; i < EE; i += gridDim.x*blockDim.x) atomicAdd(&deg[eidx[EE + i]], 1);
}

__global__ void final_kernel(const float* __restrict__ hmaxf, const float* __restrict__ fw,
                             const float* __restrict__ fb, float* __restrict__ out){
    int t = blockIdx.x*blockDim.x + threadIdx.x;
    if (t >= NN*4) return;
    int n = t >> 2, o = t & 3;
    float acc = fb[o];
    const float* hr = hmaxf + n*128;
    #pragma unroll 16
    for (int c = 0; c < 128; ++c) acc += hr[c] * fw[c*4 + o];
    out[t] = acc;
}

extern "C" void kernel_launch(void* const* d_in, const int* in_sizes, int n_in,
                              void* d_out, int out_size, void* d_ws, size_t ws_size,
                              hipStream_t stream)
{
    (void)in_sizes; (void)n_in; (void)out_size; (void)ws_size;
    const float* x      = (const float*)d_in[0];
    const float* eattr  = (const float*)d_in[1];
    const int*   eidx   = (const int*)d_in[2];
    const float* node_w = (const float*)d_in[3];
    const float* node_b = (const float*)d_in[4];
    const float* edge_w = (const float*)d_in[5];
    const float* edge_b = (const float*)d_in[6];
    const float* msg_w1 = (const float*)d_in[7];
    const float* msg_b1 = (const float*)d_in[8];
    const float* msg_w2 = (const float*)d_in[9];
    const float* msg_b2 = (const float*)d_in[10];
    const float* upd_w1 = (const float*)d_in[11];
    const float* upd_b1 = (const float*)d_in[12];
    const float* upd_w2 = (const float*)d_in[13];
    const float* upd_b2 = (const float*)d_in[14];
    const float* fw     = (const float*)d_in[15];
    const float* fb     = (const float*)d_in[16];
    float* out = (float*)d_out;

    // workspace: ~61.7 MB
    char* ws = (char*)d_ws;
    u16*   hbf  = (u16*)ws;   ws += (size_t)NN*128*2;    // 10.24 MB
    u16*   mhb  = (u16*)ws;   ws += (size_t)NN*128*2;    // 10.24 MB
    float* hmax = (float*)ws; ws += (size_t)NN*128*4;    // 20.48 MB
    float* aggr = (float*)ws; ws += (size_t)NN*128*4;    // 20.48 MB
    int*   deg  = (int*)ws;   ws += (size_t)NN*4;        //  0.16 MB
    float* W1p  = (float*)ws; ws += (size_t)2*8*256*4;   //  16 KB
    float* b1p  = (float*)ws; ws += (size_t)2*256*4;     //   2 KB

    hipFuncSetAttribute(reinterpret_cast<const void*>(&mlp_kernel<0>),
                        hipFuncAttributeMaxDynamicSharedMemorySize, SMEM_BYTES);
    hipFuncSetAttribute(reinterpret_cast<const void*>(&mlp_kernel<1>),
                        hipFuncAttributeMaxDynamicSharedMemorySize, SMEM_BYTES);
    hipFuncSetAttribute(reinterpret_cast<const void*>(&mlp_kernel<2>),
                        hipFuncAttributeMaxDynamicSharedMemorySize, SMEM_BYTES);

    hipMemsetAsync(deg, 0, (size_t)NN*4, stream);
    lift_kernel<<<2048, 256, 0, stream>>>(x, node_w, node_b, hbf, hmax);
    deg_kernel<<<1024, 256, 0, stream>>>(eidx, deg);
    prep_kernel<<<2, 256, 0, stream>>>(edge_w, edge_b, msg_w1, msg_b1, W1p, b1p);

    for (int l = 0; l < 2; ++l){
        // Mh = bf16(MLP_msg(h) + b2) per node
        mlp_kernel<0><<<160, 512, SMEM_BYTES, stream>>>(
            hbf, nullptr, nullptr, nullptr,
            msg_w1 + l*32768, msg_b1 + l*256, msg_w2 + l*32768, msg_b2 + l*128,
            nullptr, nullptr, nullptr, mhb, nullptr, NN/32);
        hipMemsetAsync(aggr, 0, (size_t)NN*128*4, stream);
        // edge pass: m = relu(edge_attr@W1' + b1')@W2 + b2 + Mh[src] -> atomic aggr[dst]
        mlp_kernel<2><<<256, 512, SMEM_BYTES, stream>>>(
            nullptr, nullptr, eattr, nullptr,
            W1p + l*2048, b1p + l*256, msg_w2 + l*32768, msg_b2 + l*128,
            eidx, mhb, aggr, nullptr, nullptr, EE/32);
        // h' = MLP_upd(h) + MLP_upd(aggr/deg); hmax = max(hmax, h'); hbf = bf16(h')
        mlp_kernel<1><<<160, 512, SMEM_BYTES, stream>>>(
            hbf, aggr, nullptr, deg,
            upd_w1 + l*32768, upd_b1 + l*256, upd_w2 + l*32768, upd_b2 + l*128,
            nullptr, nullptr, nullptr, hbf, hmax, NN/16);
    }

    final_kernel<<<625, 256, 0, stream>>>(hmax, fw, fb, out);
}